// Round 1
// baseline (1044.210 us; speedup 1.0000x reference)
//
#include <hip/hip_runtime.h>
#include <math.h>

#define N_PIX 3136
#define C_DIM 192
#define HID_DIM 384
#define BATCH 4
#define KNN 9
#define EPS_BN 1e-5f

// ---------------- workspace layout (float elements) ----------------
// h   : 12544*192  = 2408448
// sq  : 12544
// P   : 12544*384  = 4816896   (later overwritten in-place by g)
// Q   : 12544*384  = 4816896
// Wc  : 768*192    = 147456    (rows 0..383 = W1-W2, rows 384..767 = W2)
// cst : 1536       (s1,sh1[192*2] | sg,shg[384*2] | s2,sh2[192*2])
// idx : 12544*9 ints
static const size_t OFF_H   = 0;
static const size_t OFF_SQ  = OFF_H  + (size_t)12544 * 192;
static const size_t OFF_P   = OFF_SQ + 12544;
static const size_t OFF_Q   = OFF_P  + (size_t)12544 * 384;
static const size_t OFF_WC  = OFF_Q  + (size_t)12544 * 384;
static const size_t OFF_CST = OFF_WC + (size_t)768 * 192;
static const size_t OFF_IDX = OFF_CST + 1536;   // int region

// ---------------- prep: Wcomb + BN scale/shift ----------------
__global__ void k_prep(const float* __restrict__ gcn_w,
                       const float* __restrict__ bn1_g, const float* __restrict__ bn1_b,
                       const float* __restrict__ bn1_m, const float* __restrict__ bn1_v,
                       const float* __restrict__ bng_g, const float* __restrict__ bng_b,
                       const float* __restrict__ bng_m, const float* __restrict__ bng_v,
                       const float* __restrict__ bn2_g, const float* __restrict__ bn2_b,
                       const float* __restrict__ bn2_m, const float* __restrict__ bn2_v,
                       float* __restrict__ wc, float* __restrict__ cst)
{
    int t = blockIdx.x * 256 + threadIdx.x;
    if (t < 768 * 192) {
        int o = t / 192, c = t % 192;
        float v;
        if (o < 384) v = gcn_w[o * 384 + c] - gcn_w[o * 384 + 192 + c];
        else         v = gcn_w[(o - 384) * 384 + 192 + c];
        wc[t] = v;
    }
    int u = t - 768 * 192;
    if (u >= 0 && u < 768) {
        if (u < 192) {
            float s = bn1_g[u] / sqrtf(bn1_v[u] + EPS_BN);
            cst[u] = s; cst[192 + u] = bn1_b[u] - bn1_m[u] * s;
        } else if (u < 576) {
            int ch = u - 192;
            float s = bng_g[ch] / sqrtf(bng_v[ch] + EPS_BN);
            cst[384 + ch] = s; cst[768 + ch] = bng_b[ch] - bng_m[ch] * s;
        } else {
            int ch = u - 576;
            float s = bn2_g[ch] / sqrtf(bn2_v[ch] + EPS_BN);
            cst[1152 + ch] = s; cst[1344 + ch] = bn2_b[ch] - bn2_m[ch] * s;
        }
    }
}

// ---------------- K1: h = bn1(xf @ fc1_w^T + fc1_b) ----------------
// A[m=n][k=c] = x[b][c][n]  (k-major in global -> direct float4 stage)
// B[n=o][k=c] = fc1_w[o][c]
__global__ __launch_bounds__(256) void k1_fc1_bn1(
    const float* __restrict__ x, const float* __restrict__ w,
    const float* __restrict__ bias, const float* __restrict__ cst,
    float* __restrict__ h)
{
    __shared__ float As[32][64];
    __shared__ float Bs[32][64];
    int bx = blockIdx.x;                 // 196 row tiles
    int o0 = blockIdx.y * 64;            // 3 col tiles
    int b  = bx / 49;
    int n0 = (bx % 49) * 64;
    const float* xb = x + (size_t)b * C_DIM * N_PIX;
    int t = threadIdx.x;
    int tx = t & 15, ty = t >> 4;
    float acc[4][4] = {};
    for (int kc = 0; kc < 6; ++kc) {
        #pragma unroll
        for (int p = 0; p < 2; ++p) {
            int idx = t + p * 256;
            int kk = idx >> 4, j4 = idx & 15;
            float4 v = *reinterpret_cast<const float4*>(xb + (size_t)(kc * 32 + kk) * N_PIX + n0 + j4 * 4);
            *reinterpret_cast<float4*>(&As[kk][j4 * 4]) = v;
        }
        #pragma unroll
        for (int p = 0; p < 2; ++p) {
            int idx = t + p * 256;
            int oo = idx >> 3, c4 = idx & 7;
            float4 v = *reinterpret_cast<const float4*>(w + (size_t)(o0 + oo) * C_DIM + kc * 32 + c4 * 4);
            Bs[c4 * 4 + 0][oo] = v.x; Bs[c4 * 4 + 1][oo] = v.y;
            Bs[c4 * 4 + 2][oo] = v.z; Bs[c4 * 4 + 3][oo] = v.w;
        }
        __syncthreads();
        #pragma unroll
        for (int kk = 0; kk < 32; ++kk) {
            float4 av = *reinterpret_cast<const float4*>(&As[kk][ty * 4]);
            float4 bv = *reinterpret_cast<const float4*>(&Bs[kk][tx * 4]);
            float a[4] = {av.x, av.y, av.z, av.w};
            float bb[4] = {bv.x, bv.y, bv.z, bv.w};
            #pragma unroll
            for (int i = 0; i < 4; ++i)
                #pragma unroll
                for (int j = 0; j < 4; ++j) acc[i][j] += a[i] * bb[j];
        }
        __syncthreads();
    }
    #pragma unroll
    for (int i = 0; i < 4; ++i) {
        int n = n0 + ty * 4 + i;
        size_t r = (size_t)b * N_PIX + n;
        float vals[4];
        #pragma unroll
        for (int j = 0; j < 4; ++j) {
            int o = o0 + tx * 4 + j;
            vals[j] = (acc[i][j] + bias[o]) * cst[o] + cst[192 + o];
        }
        *reinterpret_cast<float4*>(h + r * C_DIM + o0 + tx * 4) =
            make_float4(vals[0], vals[1], vals[2], vals[3]);
    }
}

// ---------------- K1b: sq[r] = sum_c h[r][c]^2 ----------------
__global__ __launch_bounds__(256) void k_sq(const float* __restrict__ h, float* __restrict__ sq)
{
    int r = blockIdx.x * 256 + threadIdx.x;
    const float* hr = h + (size_t)r * C_DIM;
    float s = 0.f;
    #pragma unroll
    for (int c = 0; c < C_DIM; c += 4) {
        float4 v = *reinterpret_cast<const float4*>(hr + c);
        s += v.x * v.x + v.y * v.y + v.z * v.z + v.w * v.w;
    }
    sq[r] = s;
}

// ---------------- K2: P = h@Wd^T + gcn_b ; Q = h@W2^T ----------------
// A[m=r][k=c] = h[r][c] (m-major -> transpose stage), B = Wc[768][192]
__global__ __launch_bounds__(256) void k2_pq(
    const float* __restrict__ h, const float* __restrict__ wc,
    const float* __restrict__ gcnb, float* __restrict__ P, float* __restrict__ Q)
{
    __shared__ float As[32][64];
    __shared__ float Bs[32][64];
    int r0 = blockIdx.x * 64;
    int o0 = blockIdx.y * 64;            // 0..704
    int t = threadIdx.x;
    int tx = t & 15, ty = t >> 4;
    float acc[4][4] = {};
    for (int kc = 0; kc < 6; ++kc) {
        #pragma unroll
        for (int p = 0; p < 2; ++p) {
            int idx = t + p * 256;
            int j = idx >> 3, c4 = idx & 7;
            float4 v = *reinterpret_cast<const float4*>(h + (size_t)(r0 + j) * C_DIM + kc * 32 + c4 * 4);
            As[c4 * 4 + 0][j] = v.x; As[c4 * 4 + 1][j] = v.y;
            As[c4 * 4 + 2][j] = v.z; As[c4 * 4 + 3][j] = v.w;
        }
        #pragma unroll
        for (int p = 0; p < 2; ++p) {
            int idx = t + p * 256;
            int oo = idx >> 3, c4 = idx & 7;
            float4 v = *reinterpret_cast<const float4*>(wc + (size_t)(o0 + oo) * C_DIM + kc * 32 + c4 * 4);
            Bs[c4 * 4 + 0][oo] = v.x; Bs[c4 * 4 + 1][oo] = v.y;
            Bs[c4 * 4 + 2][oo] = v.z; Bs[c4 * 4 + 3][oo] = v.w;
        }
        __syncthreads();
        #pragma unroll
        for (int kk = 0; kk < 32; ++kk) {
            float4 av = *reinterpret_cast<const float4*>(&As[kk][ty * 4]);
            float4 bv = *reinterpret_cast<const float4*>(&Bs[kk][tx * 4]);
            float a[4] = {av.x, av.y, av.z, av.w};
            float bb[4] = {bv.x, bv.y, bv.z, bv.w};
            #pragma unroll
            for (int i = 0; i < 4; ++i)
                #pragma unroll
                for (int j = 0; j < 4; ++j) acc[i][j] += a[i] * bb[j];
        }
        __syncthreads();
    }
    bool isP = (o0 < HID_DIM);
    #pragma unroll
    for (int i = 0; i < 4; ++i) {
        size_t r = (size_t)(r0 + ty * 4 + i);
        int ocb = o0 + tx * 4;
        float vals[4];
        #pragma unroll
        for (int j = 0; j < 4; ++j)
            vals[j] = acc[i][j] + (isP ? gcnb[ocb + j] : 0.0f);
        float4 vv = make_float4(vals[0], vals[1], vals[2], vals[3]);
        if (isP) *reinterpret_cast<float4*>(P + r * HID_DIM + ocb) = vv;
        else     *reinterpret_cast<float4*>(Q + r * HID_DIM + (ocb - HID_DIM)) = vv;
    }
}

// ---------------- K3: fused pairwise-dist + top-9 ----------------
__global__ __launch_bounds__(256) void k3_knn(
    const float* __restrict__ h, const float* __restrict__ sq, int* __restrict__ idxout)
{
    __shared__ float As[32][64];
    __shared__ float Bs[32][64];
    int bx = blockIdx.x;                  // 196 = 4 batches * 49 strips
    int b  = bx / 49;
    int n0 = (bx % 49) * 64;
    const float* hb  = h  + (size_t)b * N_PIX * C_DIM;
    const float* sqb = sq + (size_t)b * N_PIX;
    int t = threadIdx.x;
    int tx = t & 15, ty = t >> 4;

    // sorted ascending top-9 (u64 keys: monotone-dist<<32 | m) — static indexing only
    unsigned long long cand[4][KNN];
    #pragma unroll
    for (int i = 0; i < 4; ++i)
        #pragma unroll
        for (int q = 0; q < KNN; ++q) cand[i][q] = ~0ull;

    float sqn[4];
    #pragma unroll
    for (int i = 0; i < 4; ++i) sqn[i] = sqb[n0 + ty * 4 + i];

    for (int mt = 0; mt < 49; ++mt) {
        int m0 = mt * 64;
        float acc[4][4] = {};
        for (int kc = 0; kc < 6; ++kc) {
            #pragma unroll
            for (int p = 0; p < 2; ++p) {
                int idx = t + p * 256;
                int j = idx >> 3, c4 = idx & 7;
                float4 va = *reinterpret_cast<const float4*>(hb + (size_t)(n0 + j) * C_DIM + kc * 32 + c4 * 4);
                As[c4 * 4 + 0][j] = va.x; As[c4 * 4 + 1][j] = va.y;
                As[c4 * 4 + 2][j] = va.z; As[c4 * 4 + 3][j] = va.w;
                float4 vb = *reinterpret_cast<const float4*>(hb + (size_t)(m0 + j) * C_DIM + kc * 32 + c4 * 4);
                Bs[c4 * 4 + 0][j] = vb.x; Bs[c4 * 4 + 1][j] = vb.y;
                Bs[c4 * 4 + 2][j] = vb.z; Bs[c4 * 4 + 3][j] = vb.w;
            }
            __syncthreads();
            #pragma unroll
            for (int kk = 0; kk < 32; ++kk) {
                float4 av = *reinterpret_cast<const float4*>(&As[kk][ty * 4]);
                float4 bv = *reinterpret_cast<const float4*>(&Bs[kk][tx * 4]);
                float a[4] = {av.x, av.y, av.z, av.w};
                float bb[4] = {bv.x, bv.y, bv.z, bv.w};
                #pragma unroll
                for (int i = 0; i < 4; ++i)
                    #pragma unroll
                    for (int j = 0; j < 4; ++j) acc[i][j] += a[i] * bb[j];
            }
            __syncthreads();
        }
        // top-k update: dist = (sq_n - 2*dot) + sq_m, same form as reference
        #pragma unroll
        for (int j = 0; j < 4; ++j) {
            int m = m0 + tx * 4 + j;
            float sqm = sqb[m];
            #pragma unroll
            for (int i = 0; i < 4; ++i) {
                float dist = (sqn[i] - 2.0f * acc[i][j]) + sqm;
                unsigned u = __float_as_uint(dist);
                u = (u & 0x80000000u) ? ~u : (u | 0x80000000u);
                unsigned long long key = ((unsigned long long)u << 32) | (unsigned)m;
                if (key < cand[i][KNN - 1]) {
                    cand[i][KNN - 1] = key;
                    #pragma unroll
                    for (int q = KNN - 1; q > 0; --q) {
                        unsigned long long lo = cand[i][q - 1], hi = cand[i][q];
                        if (hi < lo) { cand[i][q - 1] = hi; cand[i][q] = lo; }
                    }
                }
            }
        }
    }
    // merge 16 partial lists per row via u64 min-reduce over the 16 contiguous lanes
    #pragma unroll
    for (int i = 0; i < 4; ++i) {
        int n = n0 + ty * 4 + i;
        for (int r = 0; r < KNN; ++r) {
            unsigned long long my = cand[i][0];
            unsigned long long g = my;
            #pragma unroll
            for (int s = 1; s < 16; s <<= 1) {
                unsigned long long o = __shfl_xor(g, s);
                if (o < g) g = o;
            }
            if (g == my) {            // unique keys: exactly one lane pops
                #pragma unroll
                for (int q = 0; q < KNN - 1; ++q) cand[i][q] = cand[i][q + 1];
                cand[i][KNN - 1] = ~0ull;
            }
            if (tx == 0)
                idxout[((size_t)b * N_PIX + n) * KNN + r] = (int)(g & 0xffffffffu);
        }
    }
}

// ---------------- K4: g = gelu(bn_g(P + max_k Q[idx[k]])) (in-place into P) ----------------
__global__ __launch_bounds__(384) void k4_agg(
    float* __restrict__ P, const float* __restrict__ Q,
    const int* __restrict__ idx, const float* __restrict__ cst)
{
    int blk = blockIdx.x;
    int b = blk / N_PIX;
    size_t row = (size_t)blk;
    const int* id = idx + row * KNN;
    int o = threadIdx.x;
    const float* Qb = Q + (size_t)b * N_PIX * HID_DIM;
    float v = -INFINITY;
    #pragma unroll
    for (int k = 0; k < KNN; ++k)
        v = fmaxf(v, Qb[(size_t)id[k] * HID_DIM + o]);
    float gp = P[row * HID_DIM + o] + v;
    float y = gp * cst[384 + o] + cst[768 + o];
    float ge = 0.5f * y * (1.0f + erff(y * 0.70710678118654752f));
    P[row * HID_DIM + o] = ge;
}

// ---------------- K5: out = bn2(g @ fc2_w^T + fc2_b) + x, written as (B,C,N) ----------------
__global__ __launch_bounds__(256) void k5_fc2_bn2(
    const float* __restrict__ g, const float* __restrict__ w,
    const float* __restrict__ bias, const float* __restrict__ cst,
    const float* __restrict__ x, float* __restrict__ out)
{
    __shared__ float As[32][64];
    __shared__ float Bs[32][64];
    int bx = blockIdx.x;                 // 196 row tiles
    int c0 = blockIdx.y * 64;            // 3 col tiles
    int b  = bx / 49;
    int n0 = (bx % 49) * 64;
    int r0 = bx * 64;
    int t = threadIdx.x;
    int tx = t & 15, ty = t >> 4;
    float acc[4][4] = {};
    for (int kc = 0; kc < 12; ++kc) {
        #pragma unroll
        for (int p = 0; p < 2; ++p) {
            int idx = t + p * 256;
            int j = idx >> 3, c4 = idx & 7;
            float4 v = *reinterpret_cast<const float4*>(g + (size_t)(r0 + j) * HID_DIM + kc * 32 + c4 * 4);
            As[c4 * 4 + 0][j] = v.x; As[c4 * 4 + 1][j] = v.y;
            As[c4 * 4 + 2][j] = v.z; As[c4 * 4 + 3][j] = v.w;
        }
        #pragma unroll
        for (int p = 0; p < 2; ++p) {
            int idx = t + p * 256;
            int oo = idx >> 3, c4 = idx & 7;
            float4 v = *reinterpret_cast<const float4*>(w + (size_t)(c0 + oo) * HID_DIM + kc * 32 + c4 * 4);
            Bs[c4 * 4 + 0][oo] = v.x; Bs[c4 * 4 + 1][oo] = v.y;
            Bs[c4 * 4 + 2][oo] = v.z; Bs[c4 * 4 + 3][oo] = v.w;
        }
        __syncthreads();
        #pragma unroll
        for (int kk = 0; kk < 32; ++kk) {
            float4 av = *reinterpret_cast<const float4*>(&As[kk][ty * 4]);
            float4 bv = *reinterpret_cast<const float4*>(&Bs[kk][tx * 4]);
            float a[4] = {av.x, av.y, av.z, av.w};
            float bb[4] = {bv.x, bv.y, bv.z, bv.w};
            #pragma unroll
            for (int i = 0; i < 4; ++i)
                #pragma unroll
                for (int j = 0; j < 4; ++j) acc[i][j] += a[i] * bb[j];
        }
        __syncthreads();
    }
    #pragma unroll
    for (int i = 0; i < 4; ++i) {
        int n = n0 + ty * 4 + i;
        #pragma unroll
        for (int j = 0; j < 4; ++j) {
            int c = c0 + tx * 4 + j;
            size_t a = (size_t)b * C_DIM * N_PIX + (size_t)c * N_PIX + n;
            float y = (acc[i][j] + bias[c]) * cst[1152 + c] + cst[1344 + c] + x[a];
            out[a] = y;
        }
    }
}

extern "C" void kernel_launch(void* const* d_in, const int* in_sizes, int n_in,
                              void* d_out, int out_size, void* d_ws, size_t ws_size,
                              hipStream_t stream)
{
    const float* x      = (const float*)d_in[0];
    const float* fc1_w  = (const float*)d_in[1];
    const float* fc1_b  = (const float*)d_in[2];
    const float* bn1_g  = (const float*)d_in[3];
    const float* bn1_b  = (const float*)d_in[4];
    const float* bn1_m  = (const float*)d_in[5];
    const float* bn1_v  = (const float*)d_in[6];
    const float* gcn_w  = (const float*)d_in[7];
    const float* gcn_b  = (const float*)d_in[8];
    const float* bng_g  = (const float*)d_in[9];
    const float* bng_b  = (const float*)d_in[10];
    const float* bng_m  = (const float*)d_in[11];
    const float* bng_v  = (const float*)d_in[12];
    const float* fc2_w  = (const float*)d_in[13];
    const float* fc2_b  = (const float*)d_in[14];
    const float* bn2_g  = (const float*)d_in[15];
    const float* bn2_b  = (const float*)d_in[16];
    const float* bn2_m  = (const float*)d_in[17];
    const float* bn2_v  = (const float*)d_in[18];
    float* out = (float*)d_out;

    float* ws  = (float*)d_ws;
    float* h   = ws + OFF_H;
    float* sq  = ws + OFF_SQ;
    float* P   = ws + OFF_P;
    float* Q   = ws + OFF_Q;
    float* wc  = ws + OFF_WC;
    float* cst = ws + OFF_CST;
    int*   idx = (int*)(ws + OFF_IDX);

    k_prep<<<579, 256, 0, stream>>>(gcn_w, bn1_g, bn1_b, bn1_m, bn1_v,
                                    bng_g, bng_b, bng_m, bng_v,
                                    bn2_g, bn2_b, bn2_m, bn2_v, wc, cst);
    k1_fc1_bn1<<<dim3(196, 3), 256, 0, stream>>>(x, fc1_w, fc1_b, cst, h);
    k_sq<<<49, 256, 0, stream>>>(h, sq);
    k2_pq<<<dim3(196, 12), 256, 0, stream>>>(h, wc, gcn_b, P, Q);
    k3_knn<<<196, 256, 0, stream>>>(h, sq, idx);
    k4_agg<<<12544, 384, 0, stream>>>(P, Q, idx, cst);
    k5_fc2_bn2<<<dim3(196, 3), 256, 0, stream>>>(P, fc2_w, fc2_b, cst, x, out);
}